// Round 4
// baseline (342.486 us; speedup 1.0000x reference)
//
#include <hip/hip_runtime.h>
#include <math.h>

// x: (4,16,256,32,64) f32 -> NS=64 samples, CD=256 channels, HW=2048 positions
#define NS 64
#define CD 256
#define HW 2048
#define MD 1024
#define SAMPLE (CD * HW)
#define LN_EPS 1e-5f

#define PB 64            // positions per block
#define MC 128           // m-chunk
#define NCHUNK (MD / MC) // 8

typedef float f32x4 __attribute__((ext_vector_type(4)));
typedef long i64;

// XOR swizzle key: byte-bits 4-6
__device__ __forceinline__ int swz(int p) { return ((p ^ (p >> 2)) & 7) << 4; }

// ---------------- weight prep: f32 -> fp8 e4m3, transposed ----------------
__global__ __launch_bounds__(256) void k_prep(const float* __restrict__ w_in,
                                              const float* __restrict__ w_out,
                                              unsigned char* __restrict__ w_in8,
                                              unsigned char* __restrict__ w_out8) {
  int id = blockIdx.x * 256 + threadIdx.x;  // 0..131071
  if (id < 65536) {
    int m = id >> 6, c0 = (id & 63) * 4;
    float a = w_in[(size_t)(c0 + 0) * MD + m];
    float b = w_in[(size_t)(c0 + 1) * MD + m];
    float c = w_in[(size_t)(c0 + 2) * MD + m];
    float d = w_in[(size_t)(c0 + 3) * MD + m];
    int r = __builtin_amdgcn_cvt_pk_fp8_f32(a, b, 0, false);
    r = __builtin_amdgcn_cvt_pk_fp8_f32(c, d, r, true);
    ((int*)w_in8)[id] = r;  // [m][c]
  } else {
    int j = id - 65536;
    int c = j >> 8, m0 = (j & 255) * 4;
    float a = w_out[(size_t)(m0 + 0) * CD + c];
    float b = w_out[(size_t)(m0 + 1) * CD + c];
    float cc = w_out[(size_t)(m0 + 2) * CD + c];
    float d = w_out[(size_t)(m0 + 3) * CD + c];
    int r = __builtin_amdgcn_cvt_pk_fp8_f32(a, b, 0, false);
    r = __builtin_amdgcn_cvt_pk_fp8_f32(cc, d, r, true);
    ((int*)w_out8)[j] = r;  // [c][m]
  }
}

// ---------------- LN stats, stage 1 ----------------
__global__ __launch_bounds__(256) void k_stats1(const float* __restrict__ x,
                                                double* __restrict__ partial) {
  int s = blockIdx.x >> 3, sl = blockIdx.x & 7;
  const float4* p = (const float4*)(x + (size_t)s * SAMPLE + (size_t)sl * 65536);
  double sum = 0.0, ssq = 0.0;
  for (int i = 0; i < 64; ++i) {
    float4 v = p[i * 256 + threadIdx.x];
    sum += (double)v.x + (double)v.y + (double)v.z + (double)v.w;
    ssq += (double)v.x * v.x + (double)v.y * v.y + (double)v.z * v.z + (double)v.w * v.w;
  }
  for (int off = 32; off; off >>= 1) {
    sum += __shfl_down(sum, off);
    ssq += __shfl_down(ssq, off);
  }
  __shared__ double red[4][2];
  int wv = threadIdx.x >> 6, ln = threadIdx.x & 63;
  if (ln == 0) { red[wv][0] = sum; red[wv][1] = ssq; }
  __syncthreads();
  if (threadIdx.x == 0) {
    for (int i = 1; i < 4; ++i) { sum += red[i][0]; ssq += red[i][1]; }
    partial[blockIdx.x * 2] = sum;
    partial[blockIdx.x * 2 + 1] = ssq;
  }
}

// ---------------- LN stats, stage 2 ----------------
__global__ void k_stats2(const double* __restrict__ partial, float* __restrict__ stats) {
  int s = threadIdx.x;  // 64 threads
  double sum = 0.0, ssq = 0.0;
  for (int i = 0; i < 8; ++i) {
    sum += partial[(s * 8 + i) * 2];
    ssq += partial[(s * 8 + i) * 2 + 1];
  }
  double mean = sum / (double)SAMPLE;
  double var = ssq / (double)SAMPLE - mean * mean;
  stats[s * 2] = (float)mean;
  stats[s * 2 + 1] = (float)(1.0 / sqrt(var + (double)LN_EPS));
}

// ---------------- fused LN + MLP + layer-scale + residual ----------------
// PB=64/block, 2048 blocks, 8 waves. Wave w: GEMM1 m-rows [16w,16w+16);
// GEMM2 c-cols [32w,32w+32). Y B-frags for kk=0..3 cached in 16 i64 regs
// (Ysh is immutable -> read once, reuse all 8 chunks). Pipelined chunk loop:
// GEMM1(ch) -> GELU(ch) -> GEMM2(ch-1) -> barrier (GELU VALU overlaps GEMM2
// MFMA in the scheduling window; barrier after a long mixed-pipe stretch).
__global__ __launch_bounds__(512, 4) void k_fused(
    const float* __restrict__ x, const float* __restrict__ ln_w, const float* __restrict__ ln_b,
    const float* __restrict__ b_in, const float* __restrict__ b_out, const float* __restrict__ gamma,
    const unsigned char* __restrict__ w_in8, const unsigned char* __restrict__ w_out8,
    const float* __restrict__ stats, float* __restrict__ out) {
  __shared__ unsigned char Ysh[64 * 256];       // [p][c] fp8, swizzled
  __shared__ unsigned char Tsh[2][64 * 128];    // [p][m] fp8, swizzled, dbuf

  const int tid = threadIdx.x;
  const int s = blockIdx.x >> 5;
  const int p0 = (blockIdx.x & 31) * PB;
  const float mu = stats[s * 2], rstd = stats[s * 2 + 1];
  const float a_ln = rstd, c_ln = -mu * rstd;
  const size_t xbase = (size_t)s * SAMPLE;

  // ---- stage Ysh: normalize + affine, transpose (c,p)->(p,c), cvt fp8 ----
  #pragma unroll
  for (int it = 0; it < 2; ++it) {
    int bid = it * 512 + tid;               // 1024 4x4 micro-blocks
    int c0 = (bid >> 4) * 4, pp = (bid & 15) * 4;
    float yv[4][4];
    #pragma unroll
    for (int i = 0; i < 4; ++i) {
      size_t off = (size_t)(c0 + i) * HW + p0 + pp;
      float4 xv = *(const float4*)(x + xbase + off);
      float4 lw = *(const float4*)(ln_w + off);
      float4 lb = *(const float4*)(ln_b + off);
      yv[i][0] = fmaf(fmaf(xv.x, a_ln, c_ln), lw.x, lb.x);
      yv[i][1] = fmaf(fmaf(xv.y, a_ln, c_ln), lw.y, lb.y);
      yv[i][2] = fmaf(fmaf(xv.z, a_ln, c_ln), lw.z, lb.z);
      yv[i][3] = fmaf(fmaf(xv.w, a_ln, c_ln), lw.w, lb.w);
    }
    #pragma unroll
    for (int j = 0; j < 4; ++j) {
      int p = pp + j;
      int r = __builtin_amdgcn_cvt_pk_fp8_f32(yv[0][j], yv[1][j], 0, false);
      r = __builtin_amdgcn_cvt_pk_fp8_f32(yv[2][j], yv[3][j], r, true);
      *(int*)&Ysh[p * 256 + (c0 ^ swz(p))] = r;
    }
  }

  const int lane = tid & 63, l15 = lane & 15, l4 = lane >> 4;
  const int w = tid >> 6;

  f32x4 acc2[4][2] = {};  // 64p x 32c per wave, persistent

  __syncthreads();  // Ysh ready (immutable hereafter)

  // ---- cache Y B-frags for kk=0..3 in registers (reused all 8 chunks) ----
  i64 breg[16];
  #pragma unroll
  for (int kk = 0; kk < 4; ++kk)
    #pragma unroll
    for (int pi = 0; pi < 4; ++pi) {
      int p = pi * 16 + l15;
      breg[kk * 4 + pi] = *(const i64*)&Ysh[p * 256 + ((kk * 32 + l4 * 8) ^ swz(p))];
    }

  const unsigned char* Arow = w_in8 + (size_t)(16 * w + l15) * CD + l4 * 8;
  const unsigned char* Brow = w_out8 + (size_t)(32 * w + l15) * MD + l4 * 8;

  for (int ch = 0; ch < NCHUNK; ++ch) {
    const int m0 = ch * MC;
    unsigned char* T = Tsh[ch & 1];

    // ---- GEMM1(ch): D1[m][p], wave slice 16m x 64p, K=256 ----
    f32x4 acc1[4] = {};
    #pragma unroll
    for (int kk = 0; kk < 8; ++kk) {
      i64 a = *(const i64*)(Arow + (size_t)m0 * CD + kk * 32);
      #pragma unroll
      for (int pi = 0; pi < 4; ++pi) {
        i64 b;
        if (kk < 4) {
          b = breg[kk * 4 + pi];
        } else {
          int p = pi * 16 + l15;
          b = *(const i64*)&Ysh[p * 256 + ((kk * 32 + l4 * 8) ^ swz(p))];
        }
        acc1[pi] = __builtin_amdgcn_mfma_f32_16x16x32_fp8_fp8(a, b, acc1[pi], 0, 0, 0);
      }
    }

    // ---- epilogue1(ch): +b_in, sigmoid-GELU, pack fp8 -> T[p][m] ----
    const float4 bi = *(const float4*)&b_in[m0 + 16 * w + 4 * l4];
    const int mcol = 16 * w + 4 * l4;
    #pragma unroll
    for (int pi = 0; pi < 4; ++pi) {
      int p = pi * 16 + l15;
      float g[4];
      #pragma unroll
      for (int r = 0; r < 4; ++r) {
        float t = acc1[pi][r] + ((const float*)&bi)[r];
        g[r] = t * __builtin_amdgcn_rcpf(1.0f + __expf(-1.702f * t));
      }
      int pk = __builtin_amdgcn_cvt_pk_fp8_f32(g[0], g[1], 0, false);
      pk = __builtin_amdgcn_cvt_pk_fp8_f32(g[2], g[3], pk, true);
      *(int*)&T[p * 128 + (mcol ^ swz(p))] = pk;
    }

    // ---- GEMM2(ch-1): acc2 += T_prev x w_out chunk; independent of epi1 ----
    if (ch) {
      const int m0p = m0 - MC;
      const unsigned char* Tp = Tsh[(ch - 1) & 1];
      #pragma unroll
      for (int kk = 0; kk < 4; ++kk) {
        i64 b2a = *(const i64*)(Brow + m0p + kk * 32);
        i64 b2b = *(const i64*)(Brow + (size_t)16 * MD + m0p + kk * 32);
        i64 a2[4];
        #pragma unroll
        for (int mi = 0; mi < 4; ++mi) {
          int p = mi * 16 + l15;
          a2[mi] = *(const i64*)&Tp[p * 128 + ((kk * 32 + l4 * 8) ^ swz(p))];
        }
        #pragma unroll
        for (int mi = 0; mi < 4; ++mi) {
          acc2[mi][0] = __builtin_amdgcn_mfma_f32_16x16x32_fp8_fp8(a2[mi], b2a, acc2[mi][0], 0, 0, 0);
          acc2[mi][1] = __builtin_amdgcn_mfma_f32_16x16x32_fp8_fp8(a2[mi], b2b, acc2[mi][1], 0, 0, 0);
        }
      }
    }

    __syncthreads();  // T(ch) writes complete; T_prev reads complete
  }

  // ---- drain GEMM2 for last chunk ----
  {
    const int m0p = (NCHUNK - 1) * MC;
    const unsigned char* Tp = Tsh[(NCHUNK - 1) & 1];
    #pragma unroll
    for (int kk = 0; kk < 4; ++kk) {
      i64 b2a = *(const i64*)(Brow + m0p + kk * 32);
      i64 b2b = *(const i64*)(Brow + (size_t)16 * MD + m0p + kk * 32);
      i64 a2[4];
      #pragma unroll
      for (int mi = 0; mi < 4; ++mi) {
        int p = mi * 16 + l15;
        a2[mi] = *(const i64*)&Tp[p * 128 + ((kk * 32 + l4 * 8) ^ swz(p))];
      }
      #pragma unroll
      for (int mi = 0; mi < 4; ++mi) {
        acc2[mi][0] = __builtin_amdgcn_mfma_f32_16x16x32_fp8_fp8(a2[mi], b2a, acc2[mi][0], 0, 0, 0);
        acc2[mi][1] = __builtin_amdgcn_mfma_f32_16x16x32_fp8_fp8(a2[mi], b2b, acc2[mi][1], 0, 0, 0);
      }
    }
  }

  // ---- epilogue: out = x + gamma_c * (v + b_out_c) ----
  #pragma unroll
  for (int ni = 0; ni < 2; ++ni) {
    int cc = 32 * w + 16 * ni + l15;
    float gm = gamma[cc], bo = b_out[cc];
    #pragma unroll
    for (int mi = 0; mi < 4; ++mi) {
      int p = p0 + 16 * mi + 4 * l4;
      size_t off = xbase + (size_t)cc * HW + p;
      float4 xv = *(const float4*)(x + off);
      float4 o;
      #pragma unroll
      for (int r = 0; r < 4; ++r)
        ((float*)&o)[r] = ((const float*)&xv)[r] + gm * (acc2[mi][ni][r] + bo);
      *(float4*)(out + off) = o;
    }
  }
}

extern "C" void kernel_launch(void* const* d_in, const int* in_sizes, int n_in,
                              void* d_out, int out_size, void* d_ws, size_t ws_size,
                              hipStream_t stream) {
  const float* x = (const float*)d_in[0];
  const float* ln_w = (const float*)d_in[1];
  const float* ln_b = (const float*)d_in[2];
  const float* w_in = (const float*)d_in[3];
  const float* b_in = (const float*)d_in[4];
  const float* w_out = (const float*)d_in[5];
  const float* b_out = (const float*)d_in[6];
  const float* gamma = (const float*)d_in[7];
  float* out = (float*)d_out;

  char* ws = (char*)d_ws;
  unsigned char* w_in8 = (unsigned char*)ws;              // 256 KB [m][c]
  unsigned char* w_out8 = (unsigned char*)(ws + 262144);  // 256 KB [c][m]
  double* partial = (double*)(ws + 524288);               // 8 KB
  float* stats = (float*)(ws + 524288 + 8192);            // 512 B

  k_prep<<<512, 256, 0, stream>>>(w_in, w_out, w_in8, w_out8);
  k_stats1<<<512, 256, 0, stream>>>(x, partial);
  k_stats2<<<1, 64, 0, stream>>>(partial, stats);

  k_fused<<<2048, 512, 0, stream>>>(x, ln_w, ln_b, b_in, b_out, gamma,
                                    w_in8, w_out8, stats, out);
}

// Round 5
// 341.859 us; speedup vs baseline: 1.0018x; 1.0018x over previous
//
#include <hip/hip_runtime.h>
#include <math.h>

// x: (4,16,256,32,64) f32 -> NS=64 samples, CD=256 channels, HW=2048 positions
#define NS 64
#define CD 256
#define HW 2048
#define MD 1024
#define SAMPLE (CD * HW)
#define LN_EPS 1e-5f

#define PB 64            // positions per block
#define MC 128           // m-chunk
#define NCHUNK (MD / MC) // 8

typedef float f32x4 __attribute__((ext_vector_type(4)));
typedef long i64;

// XOR swizzle key: byte-bits 4-6
__device__ __forceinline__ int swz(int p) { return ((p ^ (p >> 2)) & 7) << 4; }

// ---------------- weight prep: f32 -> fp8 e4m3, transposed ----------------
__global__ __launch_bounds__(256) void k_prep(const float* __restrict__ w_in,
                                              const float* __restrict__ w_out,
                                              unsigned char* __restrict__ w_in8,
                                              unsigned char* __restrict__ w_out8) {
  int id = blockIdx.x * 256 + threadIdx.x;  // 0..131071
  if (id < 65536) {
    int m = id >> 6, c0 = (id & 63) * 4;
    float a = w_in[(size_t)(c0 + 0) * MD + m];
    float b = w_in[(size_t)(c0 + 1) * MD + m];
    float c = w_in[(size_t)(c0 + 2) * MD + m];
    float d = w_in[(size_t)(c0 + 3) * MD + m];
    int r = __builtin_amdgcn_cvt_pk_fp8_f32(a, b, 0, false);
    r = __builtin_amdgcn_cvt_pk_fp8_f32(c, d, r, true);
    ((int*)w_in8)[id] = r;  // [m][c]
  } else {
    int j = id - 65536;
    int c = j >> 8, m0 = (j & 255) * 4;
    float a = w_out[(size_t)(m0 + 0) * CD + c];
    float b = w_out[(size_t)(m0 + 1) * CD + c];
    float cc = w_out[(size_t)(m0 + 2) * CD + c];
    float d = w_out[(size_t)(m0 + 3) * CD + c];
    int r = __builtin_amdgcn_cvt_pk_fp8_f32(a, b, 0, false);
    r = __builtin_amdgcn_cvt_pk_fp8_f32(cc, d, r, true);
    ((int*)w_out8)[j] = r;  // [c][m]
  }
}

// ---------------- LN stats, stage 1 ----------------
__global__ __launch_bounds__(256) void k_stats1(const float* __restrict__ x,
                                                double* __restrict__ partial) {
  int s = blockIdx.x >> 3, sl = blockIdx.x & 7;
  const float4* p = (const float4*)(x + (size_t)s * SAMPLE + (size_t)sl * 65536);
  double sum = 0.0, ssq = 0.0;
  for (int i = 0; i < 64; ++i) {
    float4 v = p[i * 256 + threadIdx.x];
    sum += (double)v.x + (double)v.y + (double)v.z + (double)v.w;
    ssq += (double)v.x * v.x + (double)v.y * v.y + (double)v.z * v.z + (double)v.w * v.w;
  }
  for (int off = 32; off; off >>= 1) {
    sum += __shfl_down(sum, off);
    ssq += __shfl_down(ssq, off);
  }
  __shared__ double red[4][2];
  int wv = threadIdx.x >> 6, ln = threadIdx.x & 63;
  if (ln == 0) { red[wv][0] = sum; red[wv][1] = ssq; }
  __syncthreads();
  if (threadIdx.x == 0) {
    for (int i = 1; i < 4; ++i) { sum += red[i][0]; ssq += red[i][1]; }
    partial[blockIdx.x * 2] = sum;
    partial[blockIdx.x * 2 + 1] = ssq;
  }
}

// ---------------- LN stats, stage 2 ----------------
__global__ void k_stats2(const double* __restrict__ partial, float* __restrict__ stats) {
  int s = threadIdx.x;  // 64 threads
  double sum = 0.0, ssq = 0.0;
  for (int i = 0; i < 8; ++i) {
    sum += partial[(s * 8 + i) * 2];
    ssq += partial[(s * 8 + i) * 2 + 1];
  }
  double mean = sum / (double)SAMPLE;
  double var = ssq / (double)SAMPLE - mean * mean;
  stats[s * 2] = (float)mean;
  stats[s * 2 + 1] = (float)(1.0 / sqrt(var + (double)LN_EPS));
}

// ---------------- fused LN + MLP + layer-scale + residual ----------------
// Round-3 structure (GEMM1 -> GELU -> barrier -> GEMM2, 1 barrier/chunk, no
// software pipeline -- r4's pipeline caused scratch spills). Two latency fixes:
//  (a) breg: Ysh B-frags for kk=0..3 cached in 16 i64 (Ysh immutable; halves
//      steady-state GEMM1 LDS reads),
//  (b) GEMM2 b2 global frags issued at TOP of chunk (L2 latency completes
//      under GEMM1+GELU; __syncthreads drains vmcnt anyway).
__global__ __launch_bounds__(512, 4) void k_fused(
    const float* __restrict__ x, const float* __restrict__ ln_w, const float* __restrict__ ln_b,
    const float* __restrict__ b_in, const float* __restrict__ b_out, const float* __restrict__ gamma,
    const unsigned char* __restrict__ w_in8, const unsigned char* __restrict__ w_out8,
    const float* __restrict__ stats, float* __restrict__ out) {
  __shared__ unsigned char Ysh[64 * 256];       // [p][c] fp8, swizzled
  __shared__ unsigned char Tsh[2][64 * 128];    // [p][m] fp8, swizzled, dbuf

  const int tid = threadIdx.x;
  const int s = blockIdx.x >> 5;
  const int p0 = (blockIdx.x & 31) * PB;
  const float mu = stats[s * 2], rstd = stats[s * 2 + 1];
  const float a_ln = rstd, c_ln = -mu * rstd;
  const size_t xbase = (size_t)s * SAMPLE;

  // ---- stage Ysh: normalize + affine, transpose (c,p)->(p,c), cvt fp8 ----
  #pragma unroll
  for (int it = 0; it < 2; ++it) {
    int bid = it * 512 + tid;               // 1024 4x4 micro-blocks
    int c0 = (bid >> 4) * 4, pp = (bid & 15) * 4;
    float yv[4][4];
    #pragma unroll
    for (int i = 0; i < 4; ++i) {
      size_t off = (size_t)(c0 + i) * HW + p0 + pp;
      float4 xv = *(const float4*)(x + xbase + off);
      float4 lw = *(const float4*)(ln_w + off);
      float4 lb = *(const float4*)(ln_b + off);
      yv[i][0] = fmaf(fmaf(xv.x, a_ln, c_ln), lw.x, lb.x);
      yv[i][1] = fmaf(fmaf(xv.y, a_ln, c_ln), lw.y, lb.y);
      yv[i][2] = fmaf(fmaf(xv.z, a_ln, c_ln), lw.z, lb.z);
      yv[i][3] = fmaf(fmaf(xv.w, a_ln, c_ln), lw.w, lb.w);
    }
    #pragma unroll
    for (int j = 0; j < 4; ++j) {
      int p = pp + j;
      int r = __builtin_amdgcn_cvt_pk_fp8_f32(yv[0][j], yv[1][j], 0, false);
      r = __builtin_amdgcn_cvt_pk_fp8_f32(yv[2][j], yv[3][j], r, true);
      *(int*)&Ysh[p * 256 + (c0 ^ swz(p))] = r;
    }
  }

  const int lane = tid & 63, l15 = lane & 15, l4 = lane >> 4;
  const int w = tid >> 6;

  f32x4 acc2[4][2] = {};  // 64p x 32c per wave, persistent

  __syncthreads();  // Ysh ready (immutable hereafter)

  // ---- cache Y B-frags for kk=0..3 in registers (reused all 8 chunks) ----
  i64 breg[16];
  #pragma unroll
  for (int kk = 0; kk < 4; ++kk)
    #pragma unroll
    for (int pi = 0; pi < 4; ++pi) {
      int p = pi * 16 + l15;
      breg[kk * 4 + pi] = *(const i64*)&Ysh[p * 256 + ((kk * 32 + l4 * 8) ^ swz(p))];
    }

  const unsigned char* Arow = w_in8 + (size_t)(16 * w + l15) * CD + l4 * 8;
  const unsigned char* Brow = w_out8 + (size_t)(32 * w + l15) * MD + l4 * 8;

  for (int ch = 0; ch < NCHUNK; ++ch) {
    const int m0 = ch * MC;
    unsigned char* T = Tsh[ch & 1];

    // ---- b2 prefetch (GEMM2 B-frags), issued before GEMM1 so L2 latency
    //      completes under GEMM1+GELU ----
    i64 b2a[4], b2b[4];
    #pragma unroll
    for (int kk = 0; kk < 4; ++kk) {
      b2a[kk] = *(const i64*)(Brow + m0 + kk * 32);
      b2b[kk] = *(const i64*)(Brow + (size_t)16 * MD + m0 + kk * 32);
    }

    // ---- GEMM1(ch): D1[m][p], wave slice 16m x 64p, K=256 ----
    f32x4 acc1[4] = {};
    #pragma unroll
    for (int kk = 0; kk < 8; ++kk) {
      i64 a = *(const i64*)(Arow + (size_t)m0 * CD + kk * 32);
      #pragma unroll
      for (int pi = 0; pi < 4; ++pi) {
        i64 b;
        if (kk < 4) {
          b = breg[kk * 4 + pi];
        } else {
          int p = pi * 16 + l15;
          b = *(const i64*)&Ysh[p * 256 + ((kk * 32 + l4 * 8) ^ swz(p))];
        }
        acc1[pi] = __builtin_amdgcn_mfma_f32_16x16x32_fp8_fp8(a, b, acc1[pi], 0, 0, 0);
      }
    }

    // ---- epilogue1(ch): +b_in, sigmoid-GELU, pack fp8 -> T[p][m] ----
    const float4 bi = *(const float4*)&b_in[m0 + 16 * w + 4 * l4];
    const int mcol = 16 * w + 4 * l4;
    #pragma unroll
    for (int pi = 0; pi < 4; ++pi) {
      int p = pi * 16 + l15;
      float g[4];
      #pragma unroll
      for (int r = 0; r < 4; ++r) {
        float t = acc1[pi][r] + ((const float*)&bi)[r];
        g[r] = t * __builtin_amdgcn_rcpf(1.0f + __expf(-1.702f * t));
      }
      int pk = __builtin_amdgcn_cvt_pk_fp8_f32(g[0], g[1], 0, false);
      pk = __builtin_amdgcn_cvt_pk_fp8_f32(g[2], g[3], pk, true);
      *(int*)&T[p * 128 + (mcol ^ swz(p))] = pk;
    }

    __syncthreads();  // T(ch) ready

    // ---- GEMM2(ch): acc2 += T (64p x 128m) x w_out chunk; 64p x 32c/wave ----
    #pragma unroll
    for (int kk = 0; kk < 4; ++kk) {
      i64 a2[4];
      #pragma unroll
      for (int mi = 0; mi < 4; ++mi) {
        int p = mi * 16 + l15;
        a2[mi] = *(const i64*)&T[p * 128 + ((kk * 32 + l4 * 8) ^ swz(p))];
      }
      #pragma unroll
      for (int mi = 0; mi < 4; ++mi) {
        acc2[mi][0] = __builtin_amdgcn_mfma_f32_16x16x32_fp8_fp8(a2[mi], b2a[kk], acc2[mi][0], 0, 0, 0);
        acc2[mi][1] = __builtin_amdgcn_mfma_f32_16x16x32_fp8_fp8(a2[mi], b2b[kk], acc2[mi][1], 0, 0, 0);
      }
    }
  }

  // ---- epilogue: out = x + gamma_c * (v + b_out_c) ----
  #pragma unroll
  for (int ni = 0; ni < 2; ++ni) {
    int cc = 32 * w + 16 * ni + l15;
    float gm = gamma[cc], bo = b_out[cc];
    #pragma unroll
    for (int mi = 0; mi < 4; ++mi) {
      int p = p0 + 16 * mi + 4 * l4;
      size_t off = xbase + (size_t)cc * HW + p;
      float4 xv = *(const float4*)(x + off);
      float4 o;
      #pragma unroll
      for (int r = 0; r < 4; ++r)
        ((float*)&o)[r] = ((const float*)&xv)[r] + gm * (acc2[mi][ni][r] + bo);
      *(float4*)(out + off) = o;
    }
  }
}

extern "C" void kernel_launch(void* const* d_in, const int* in_sizes, int n_in,
                              void* d_out, int out_size, void* d_ws, size_t ws_size,
                              hipStream_t stream) {
  const float* x = (const float*)d_in[0];
  const float* ln_w = (const float*)d_in[1];
  const float* ln_b = (const float*)d_in[2];
  const float* w_in = (const float*)d_in[3];
  const float* b_in = (const float*)d_in[4];
  const float* w_out = (const float*)d_in[5];
  const float* b_out = (const float*)d_in[6];
  const float* gamma = (const float*)d_in[7];
  float* out = (float*)d_out;

  char* ws = (char*)d_ws;
  unsigned char* w_in8 = (unsigned char*)ws;              // 256 KB [m][c]
  unsigned char* w_out8 = (unsigned char*)(ws + 262144);  // 256 KB [c][m]
  double* partial = (double*)(ws + 524288);               // 8 KB
  float* stats = (float*)(ws + 524288 + 8192);            // 512 B

  k_prep<<<512, 256, 0, stream>>>(w_in, w_out, w_in8, w_out8);
  k_stats1<<<512, 256, 0, stream>>>(x, partial);
  k_stats2<<<1, 64, 0, stream>>>(partial, stats);

  k_fused<<<2048, 512, 0, stream>>>(x, ln_w, ln_b, b_in, b_out, gamma,
                                    w_in8, w_out8, stats, out);
}